// Round 1
// 622.133 us; speedup vs baseline: 1.0321x; 1.0321x over previous
//
#include <hip/hip_runtime.h>
#include <math.h>

// TCN residual block: InstanceNorm1d (no affine) -> ELU -> depthwise conv1d
// (K=3, dilation=1, pad=1) -> +bias -> +residual.
// Shapes: inp (B=32, C=384, T=8192) fp32; weight (C,1,3); bias (C,).
//
// R1: drop the 32 KB LDS row (it capped occupancy at 4 blocks/CU). The row
// lives in registers (raw[VPT]); conv neighbors come from intra-wave
// shuffles; only the 64 wave/chunk-boundary values go through a 288 B LDS
// array, published by the same barrier the stats reduction already needs.
// ELU via hardware v_exp (__expf) instead of ocml expm1f. Non-temporal
// load/store on the two 403 MB streams (touched exactly once).

typedef float f32x4 __attribute__((ext_vector_type(4)));

constexpr int T_LEN = 8192;
constexpr int C_CH  = 384;
constexpr int BLOCK = 256;
constexpr int VPT   = T_LEN / (BLOCK * 4);   // 8 float4 chunks per thread
constexpr int WAVES = BLOCK / 64;            // 4
constexpr float EPS = 1e-5f;

__device__ __forceinline__ float elu_fast(float x) {
    // exp(x)-1 via v_exp_f32; for x<=0 abs error ~1e-7 (negligible here)
    return x > 0.0f ? x : (__expf(x) - 1.0f);
}

__global__ __launch_bounds__(BLOCK)
void tcn_resblock_kernel(const float* __restrict__ inp,
                         const float* __restrict__ weight,
                         const float* __restrict__ bias,
                         float* __restrict__ out) {
    __shared__ float s_red[WAVES * 2];       // per-wave {sum, sumsq}
    __shared__ float s_lx[WAVES][VPT];       // lane-0  v.x per (wave, chunk)
    __shared__ float s_lw[WAVES][VPT];       // lane-63 v.w per (wave, chunk)

    const int row = blockIdx.x;              // row = b * C + c
    const int c   = row % C_CH;
    const float* __restrict__ in_row  = inp + (size_t)row * T_LEN;
    float* __restrict__       out_row = out + (size_t)row * T_LEN;

    const int tid  = threadIdx.x;
    const int lane = tid & 63;
    const int wave = tid >> 6;

    // ---- Pass 1: coalesced nontemporal float4 loads -> registers + stats
    f32x4 raw[VPT];
    float sum = 0.0f, sumsq = 0.0f;
#pragma unroll
    for (int k = 0; k < VPT; ++k) {
        const int idx = (k * BLOCK + tid) * 4;           // coalesced
        f32x4 v = __builtin_nontemporal_load(
            reinterpret_cast<const f32x4*>(in_row + idx));
        raw[k] = v;
        sum   += (v.x + v.y) + (v.z + v.w);
        sumsq += fmaf(v.x, v.x, fmaf(v.y, v.y, fmaf(v.z, v.z, v.w * v.w)));
        // stage only wave-boundary raw values (conv taps across wave edges)
        if (lane == 0)  s_lx[wave][k] = v.x;
        if (lane == 63) s_lw[wave][k] = v.w;
    }

    // uniform scalar loads; issue early so they hide under the reduction
    const float w0 = weight[c * 3 + 0];
    const float w1 = weight[c * 3 + 1];
    const float w2 = weight[c * 3 + 2];
    const float bi = bias[c];

    // ---- Wave (64-lane) shuffle reduction, then cross-wave via LDS
#pragma unroll
    for (int off = 32; off > 0; off >>= 1) {
        sum   += __shfl_down(sum,   off, 64);
        sumsq += __shfl_down(sumsq, off, 64);
    }
    if (lane == 0) {
        s_red[wave * 2]     = sum;
        s_red[wave * 2 + 1] = sumsq;
    }
    __syncthreads();   // publishes s_red + s_lx/s_lw

    const float tot   = (s_red[0] + s_red[2]) + (s_red[4] + s_red[6]);
    const float totsq = (s_red[1] + s_red[3]) + (s_red[5] + s_red[7]);
    const float inv_t = 1.0f / (float)T_LEN;
    const float mean  = tot * inv_t;
    const float var   = totsq * inv_t - mean * mean;
    const float rstd  = rsqrtf(var + EPS);
    const float nms   = -mean * rstd;        // normalized x = fmaf(x, rstd, nms)

    // ---- Pass 2: ELU (registers) + K=3 conv (neighbors via shuffle) + store
#pragma unroll
    for (int k = 0; k < VPT; ++k) {
        const int idx = (k * BLOCK + tid) * 4;
        const f32x4 v = raw[k];
        const float e0 = elu_fast(fmaf(v.x, rstd, nms));
        const float e1 = elu_fast(fmaf(v.y, rstd, nms));
        const float e2 = elu_fast(fmaf(v.z, rstd, nms));
        const float e3 = elu_fast(fmaf(v.w, rstd, nms));

        // left neighbor (t = idx-1): lane-1's e3; wave/chunk edges via LDS
        float el = __shfl_up(e3, 1, 64);
        if (lane == 0) {
            if (wave == 0 && k == 0) {
                el = 0.0f;                               // zero pad
            } else {
                const float lraw = (wave == 0) ? s_lw[WAVES - 1][k - 1]
                                               : s_lw[wave - 1][k];
                el = elu_fast(fmaf(lraw, rstd, nms));
            }
        }
        // right neighbor (t = idx+4): lane+1's e0; edges via LDS
        float er = __shfl_down(e0, 1, 64);
        if (lane == 63) {
            if (wave == WAVES - 1 && k == VPT - 1) {
                er = 0.0f;                               // zero pad
            } else {
                const float rraw = (wave == WAVES - 1) ? s_lx[0][k + 1]
                                                       : s_lx[wave + 1][k];
                er = elu_fast(fmaf(rraw, rstd, nms));
            }
        }

        f32x4 o;
        o.x = fmaf(w0, el, fmaf(w1, e0, fmaf(w2, e1, bi))) + v.x;
        o.y = fmaf(w0, e0, fmaf(w1, e1, fmaf(w2, e2, bi))) + v.y;
        o.z = fmaf(w0, e1, fmaf(w1, e2, fmaf(w2, e3, bi))) + v.z;
        o.w = fmaf(w0, e2, fmaf(w1, e3, fmaf(w2, er, bi))) + v.w;
        __builtin_nontemporal_store(o,
            reinterpret_cast<f32x4*>(out_row + idx));    // coalesced
    }
}

extern "C" void kernel_launch(void* const* d_in, const int* in_sizes, int n_in,
                              void* d_out, int out_size, void* d_ws, size_t ws_size,
                              hipStream_t stream) {
    const float* inp    = (const float*)d_in[0];
    const float* weight = (const float*)d_in[1];
    const float* bias   = (const float*)d_in[2];
    float* out          = (float*)d_out;

    const int rows = in_sizes[0] / T_LEN;   // B * C = 12288
    tcn_resblock_kernel<<<rows, BLOCK, 0, stream>>>(inp, weight, bias, out);
}

// Round 2
// 618.781 us; speedup vs baseline: 1.0377x; 1.0054x over previous
//
#include <hip/hip_runtime.h>
#include <math.h>

// TCN residual block: InstanceNorm1d (no affine) -> ELU -> depthwise conv1d
// (K=3, dilation=1, pad=1) -> +bias -> +residual.
// Shapes: inp (B=32, C=384, T=8192) fp32; weight (C,1,3); bias (C,).
//
// R2: occupancy/latency experiment. BLOCK 256->512 (VPT 8->4) halves the
// per-thread register row (raw = 16 VGPRs) -> target 8 waves/SIMD (100%
// occupancy). Pass 1 is a pure clustered load loop (max MLP); stats and
// wave-boundary LDS staging follow. One barrier total. Diagnostic: if
// dur_us doesn't move, the remaining time is harness re-poison overhead
// (1.6 GB fill = 250 us visible in rocprof) and the kernel is at the
// 805 MB streaming floor.

typedef float f32x4 __attribute__((ext_vector_type(4)));

constexpr int T_LEN = 8192;
constexpr int C_CH  = 384;
constexpr int BLOCK = 512;
constexpr int VPT   = T_LEN / (BLOCK * 4);   // 4 float4 chunks per thread
constexpr int WAVES = BLOCK / 64;            // 8
constexpr float EPS = 1e-5f;

__device__ __forceinline__ float elu_fast(float x) {
    // exp(x)-1 via v_exp_f32; for x<=0 abs error ~1e-7 (negligible here)
    return x > 0.0f ? x : (__expf(x) - 1.0f);
}

__global__ __launch_bounds__(BLOCK)
void tcn_resblock_kernel(const float* __restrict__ inp,
                         const float* __restrict__ weight,
                         const float* __restrict__ bias,
                         float* __restrict__ out) {
    __shared__ float s_red[WAVES * 2];       // per-wave {sum, sumsq}
    __shared__ float s_lx[WAVES][VPT];       // lane-0  v.x per (wave, chunk)
    __shared__ float s_lw[WAVES][VPT];       // lane-63 v.w per (wave, chunk)

    const int row = blockIdx.x;              // row = b * C + c
    const int c   = row % C_CH;
    const float* __restrict__ in_row  = inp + (size_t)row * T_LEN;
    float* __restrict__       out_row = out + (size_t)row * T_LEN;

    const int tid  = threadIdx.x;
    const int lane = tid & 63;
    const int wave = tid >> 6;

    // ---- Pass 1a: pure clustered nontemporal float4 loads (max MLP)
    f32x4 raw[VPT];
#pragma unroll
    for (int k = 0; k < VPT; ++k) {
        const int idx = (k * BLOCK + tid) * 4;           // coalesced
        raw[k] = __builtin_nontemporal_load(
            reinterpret_cast<const f32x4*>(in_row + idx));
    }

    // uniform scalar loads; issue early so they hide under the reduction
    const float w0 = weight[c * 3 + 0];
    const float w1 = weight[c * 3 + 1];
    const float w2 = weight[c * 3 + 2];
    const float bi = bias[c];

    // ---- Pass 1b: stats + wave/chunk-boundary staging (conv edge taps)
    float sum = 0.0f, sumsq = 0.0f;
#pragma unroll
    for (int k = 0; k < VPT; ++k) {
        const f32x4 v = raw[k];
        sum   += (v.x + v.y) + (v.z + v.w);
        sumsq += fmaf(v.x, v.x, fmaf(v.y, v.y, fmaf(v.z, v.z, v.w * v.w)));
        if (lane == 0)  s_lx[wave][k] = v.x;
        if (lane == 63) s_lw[wave][k] = v.w;
    }

    // ---- Wave (64-lane) shuffle reduction, then cross-wave via LDS
#pragma unroll
    for (int off = 32; off > 0; off >>= 1) {
        sum   += __shfl_down(sum,   off, 64);
        sumsq += __shfl_down(sumsq, off, 64);
    }
    if (lane == 0) {
        s_red[wave * 2]     = sum;
        s_red[wave * 2 + 1] = sumsq;
    }
    __syncthreads();   // publishes s_red + s_lx/s_lw

    float tot = 0.0f, totsq = 0.0f;
#pragma unroll
    for (int w = 0; w < WAVES; ++w) {
        tot   += s_red[w * 2];
        totsq += s_red[w * 2 + 1];
    }
    const float inv_t = 1.0f / (float)T_LEN;
    const float mean  = tot * inv_t;
    const float var   = totsq * inv_t - mean * mean;
    const float rstd  = rsqrtf(var + EPS);
    const float nms   = -mean * rstd;        // normalized x = fmaf(x, rstd, nms)

    // ---- Pass 2: ELU (registers) + K=3 conv (neighbors via shuffle) + store
#pragma unroll
    for (int k = 0; k < VPT; ++k) {
        const int idx = (k * BLOCK + tid) * 4;
        const f32x4 v = raw[k];
        const float e0 = elu_fast(fmaf(v.x, rstd, nms));
        const float e1 = elu_fast(fmaf(v.y, rstd, nms));
        const float e2 = elu_fast(fmaf(v.z, rstd, nms));
        const float e3 = elu_fast(fmaf(v.w, rstd, nms));

        // left neighbor (t = idx-1): lane-1's e3; wave/chunk edges via LDS
        float el = __shfl_up(e3, 1, 64);
        if (lane == 0) {
            if (wave == 0 && k == 0) {
                el = 0.0f;                               // zero pad
            } else {
                const float lraw = (wave == 0) ? s_lw[WAVES - 1][k - 1]
                                               : s_lw[wave - 1][k];
                el = elu_fast(fmaf(lraw, rstd, nms));
            }
        }
        // right neighbor (t = idx+4): lane+1's e0; edges via LDS
        float er = __shfl_down(e0, 1, 64);
        if (lane == 63) {
            if (wave == WAVES - 1 && k == VPT - 1) {
                er = 0.0f;                               // zero pad
            } else {
                const float rraw = (wave == WAVES - 1) ? s_lx[0][k + 1]
                                                       : s_lx[wave + 1][k];
                er = elu_fast(fmaf(rraw, rstd, nms));
            }
        }

        f32x4 o;
        o.x = fmaf(w0, el, fmaf(w1, e0, fmaf(w2, e1, bi))) + v.x;
        o.y = fmaf(w0, e0, fmaf(w1, e1, fmaf(w2, e2, bi))) + v.y;
        o.z = fmaf(w0, e1, fmaf(w1, e2, fmaf(w2, e3, bi))) + v.z;
        o.w = fmaf(w0, e2, fmaf(w1, e3, fmaf(w2, er, bi))) + v.w;
        __builtin_nontemporal_store(o,
            reinterpret_cast<f32x4*>(out_row + idx));    // coalesced
    }
}

extern "C" void kernel_launch(void* const* d_in, const int* in_sizes, int n_in,
                              void* d_out, int out_size, void* d_ws, size_t ws_size,
                              hipStream_t stream) {
    const float* inp    = (const float*)d_in[0];
    const float* weight = (const float*)d_in[1];
    const float* bias   = (const float*)d_in[2];
    float* out          = (float*)d_out;

    const int rows = in_sizes[0] / T_LEN;   // B * C = 12288
    tcn_resblock_kernel<<<rows, BLOCK, 0, stream>>>(inp, weight, bias, out);
}